// Round 8
// baseline (208.658 us; speedup 1.0000x reference)
//
#include <hip/hip_runtime.h>
#include <math.h>

#define EMBED 512
#define HDIM 64
#define NHEADS 8
#define SEQ_N 2048
#define SEQ_L 2048
#define BATCH 4
#define MROWS (SEQ_N*BATCH)   // 8192 rows, row index m = n*BATCH + b
#define BE (BATCH*EMBED)      // 2048 element row stride in (n,b,E) tensors

// scores scale folded into Q-projection and pe1: 1/sqrt(64) * log2(e)
#define QSCALE 0.18033688f

typedef _Float16 f16;
typedef _Float16 half8 __attribute__((ext_vector_type(8)));
typedef _Float16 half4 __attribute__((ext_vector_type(4)));
typedef _Float16 half2v __attribute__((ext_vector_type(2)));
typedef float floatx4 __attribute__((ext_vector_type(4)));
typedef float floatx16 __attribute__((ext_vector_type(16)));

static __device__ inline float fast_exp2(float x) {
#if __has_builtin(__builtin_amdgcn_exp2f)
  return __builtin_amdgcn_exp2f(x);
#else
  return __expf(x * 0.69314718056f);
#endif
}

static __device__ inline half2v pk2(float a, float b) {
#if __has_builtin(__builtin_amdgcn_cvt_pkrtz)
  return __builtin_bit_cast(half2v, __builtin_amdgcn_cvt_pkrtz(a, b));
#else
  half2v o; o[0] = (f16)a; o[1] = (f16)b; return o;
#endif
}

static __device__ inline half8 cvt8(float4 u, float4 v) {
  half2v p0 = pk2(u.x, u.y), p1 = pk2(u.z, u.w);
  half2v p2 = pk2(v.x, v.y), p3 = pk2(v.z, v.w);
  half8 o;
  o[0] = p0[0]; o[1] = p0[1]; o[2] = p1[0]; o[3] = p1[1];
  o[4] = p2[0]; o[5] = p2[1]; o[6] = p3[0]; o[7] = p3[1];
  return o;
}

// async global->LDS 16B/lane copy: LDS dest is wave-uniform base + lane*16,
// global src is per-lane. [m97 recipe, width=16]
static __device__ inline void gload16(const void* g, void* l) {
  __builtin_amdgcn_global_load_lds(
      (__attribute__((address_space(1))) void*)(g),
      (__attribute__((address_space(3))) void*)(l), 16, 0, 0);
}

// ---------------------------------------- weights fp32->fp16 (tiny, 4 MB)
// q/k/v conversion is now fused into gemm_qkv's A staging.
__global__ __launch_bounds__(256) void cvt_w(const float* __restrict__ Wq,
                                             const float* __restrict__ Wk,
                                             const float* __restrict__ Wv,
                                             const float* __restrict__ Wo,
                                             f16* __restrict__ Wb) {
  const long WSZ = (long)EMBED * EMBED;  // 2^18
  long i = ((long)blockIdx.x * 256 + threadIdx.x) * 4;
  int sel = (int)(i >> 18);
  long off = i & (WSZ - 1);
  const float* s = sel == 0 ? Wq : sel == 1 ? Wk : sel == 2 ? Wv : Wo;
  float4 f = *reinterpret_cast<const float4*>(s + off);
  half4 o; o[0] = (f16)f.x; o[1] = (f16)f.y; o[2] = (f16)f.z; o[3] = (f16)f.w;
  *reinterpret_cast<half4*>(Wb + i) = o;
}

// ---------------------------------------- fused QKV projection GEMM (128x128)
// A (q/k/v) consumed DIRECTLY as fp32: per K-step each thread loads 4 float4,
// converts via cvt_pkrtz during the MFMA phase (loads issued before compute,
// latency hidden), and ds_writes the f16 tile into the other As buffer.
// B (weights, f16) keeps the async gload16 2-phase. sel==0 pre-scaled QSCALE;
// sel==2 V-transpose epilogue through LDS (verified R4 win).
__global__ __launch_bounds__(256) void gemm_qkv(const float* __restrict__ A0,
                                                const float* __restrict__ A1,
                                                const float* __restrict__ A2,
                                                const f16* __restrict__ W0,
                                                const f16* __restrict__ W1,
                                                const f16* __restrict__ W2,
                                                const float* __restrict__ b0,
                                                const float* __restrict__ b1,
                                                const float* __restrict__ b2,
                                                f16* __restrict__ C0, f16* __restrict__ C1,
                                                f16* __restrict__ C2t) {
  __shared__ alignas(16) unsigned char gsm[34816];
  f16* As = reinterpret_cast<f16*>(gsm);            // [2][128*32]
  f16* Bs = reinterpret_cast<f16*>(gsm + 16384);    // [2][128*32]
  f16* T  = reinterpret_cast<f16*>(gsm);            // [128][136] (sel==2 epi)
  const int sel = blockIdx.y >> 2;
  const float* A = sel == 0 ? A0 : sel == 1 ? A1 : A2;
  const f16* Bt = sel == 0 ? W0 : sel == 1 ? W1 : W2;
  const float* bias = sel == 0 ? b0 : sel == 1 ? b1 : b2;
  const float scl = sel == 0 ? QSCALE : 1.0f;
  const int tid = threadIdx.x;
  const int wave = tid >> 6, lane = tid & 63, quad = lane >> 4, l16 = lane & 15;
  const int wm = wave & 1, wn = wave >> 1;
  const long m0 = (long)blockIdx.x * 128;
  const long n0 = (long)(blockIdx.y & 3) * 128;
  const int srow = lane >> 2;        // 0..15 row within 16-row chunk
  const int scol = (lane & 3) * 8;   // f16 col within 32-wide tile

  // A staging geometry: thread covers row ar = tid>>1, cols [ah, ah+16).
  const int ar = tid >> 1;
  const int ah = (tid & 1) * 16;
  const float* Agp = A + (m0 + ar) * EMBED + ah;
  const f16* Bg0 = Bt + (n0 + wave * 32 + srow) * EMBED + scol;
  const f16* Bg1 = Bt + (n0 + wave * 32 + 16 + srow) * EMBED + scol;

  // prologue: stage K-step 0
  {
    float4 a4[4];
#pragma unroll
    for (int j = 0; j < 4; ++j)
      a4[j] = *reinterpret_cast<const float4*>(Agp + j * 4);
    gload16(Bg0, &Bs[(wave * 32) * 32]);
    gload16(Bg1, &Bs[(wave * 32 + 16) * 32]);
    *reinterpret_cast<half8*>(&As[ar * 32 + ah]) = cvt8(a4[0], a4[1]);
    *reinterpret_cast<half8*>(&As[ar * 32 + ah + 8]) = cvt8(a4[2], a4[3]);
  }
  floatx4 acc[4][4] = {};
  __syncthreads();  // drains B gloads (vmcnt) + A ds_writes (lgkm)

#pragma unroll
  for (int ks = 0; ks < 16; ++ks) {
    const int cur = ks & 1;
    float4 a4[4];
    if (ks + 1 < 16) {
      const int k1 = (ks + 1) * 32;
#pragma unroll
      for (int j = 0; j < 4; ++j)
        a4[j] = *reinterpret_cast<const float4*>(Agp + k1 + j * 4);
      gload16(Bg0 + k1, &Bs[(cur ^ 1) * 4096 + (wave * 32) * 32]);
      gload16(Bg1 + k1, &Bs[(cur ^ 1) * 4096 + (wave * 32 + 16) * 32]);
    }
    half8 af[4], bf[4];
#pragma unroll
    for (int i = 0; i < 4; ++i)
      af[i] = *reinterpret_cast<const half8*>(&As[cur * 4096 + (wm * 64 + i * 16 + l16) * 32 + quad * 8]);
#pragma unroll
    for (int j = 0; j < 4; ++j)
      bf[j] = *reinterpret_cast<const half8*>(&Bs[cur * 4096 + (wn * 64 + j * 16 + l16) * 32 + quad * 8]);
#pragma unroll
    for (int i = 0; i < 4; ++i)
#pragma unroll
      for (int j = 0; j < 4; ++j)
        acc[i][j] = __builtin_amdgcn_mfma_f32_16x16x32_f16(af[i], bf[j], acc[i][j], 0, 0, 0);
    if (ks + 1 < 16) {
      // convert + publish next A tile (float4s arrived during MFMA)
      *reinterpret_cast<half8*>(&As[(cur ^ 1) * 4096 + ar * 32 + ah]) = cvt8(a4[0], a4[1]);
      *reinterpret_cast<half8*>(&As[(cur ^ 1) * 4096 + ar * 32 + ah + 8]) = cvt8(a4[2], a4[3]);
      __syncthreads();  // drains B gloads + A ds_writes; publishes buffers
    }
  }

  if (sel != 2) {
    f16* C = sel == 0 ? C0 : C1;
#pragma unroll
    for (int i = 0; i < 4; ++i)
#pragma unroll
      for (int r = 0; r < 4; ++r) {
        long row = m0 + wm * 64 + i * 16 + quad * 4 + r;
#pragma unroll
        for (int j = 0; j < 4; ++j) {
          long col = n0 + wn * 64 + j * 16 + l16;
          float val = (acc[i][j][r] + bias[col]) * scl;
          C[row * EMBED + col] = (f16)val;
        }
      }
  } else {
    __syncthreads();  // done reading As/Bs
#pragma unroll
    for (int i = 0; i < 4; ++i)
#pragma unroll
      for (int r = 0; r < 4; ++r) {
        int mrow = wm * 64 + i * 16 + quad * 4 + r;
        int bq = mrow & 3, lt = mrow >> 2;
#pragma unroll
        for (int j = 0; j < 4; ++j) {
          int col = wn * 64 + j * 16 + l16;
          float val = acc[i][j][r] + bias[n0 + col];
          T[col * 136 + bq * 32 + lt] = (f16)val;
        }
      }
    __syncthreads();
    const int h0 = (int)(n0 >> 6);   // first head of this col-tile (2 heads)
    const long lbase = m0 >> 2;      // l-token base of this row-tile
#pragma unroll
    for (int it = 0; it < 8; ++it) {
      int f = it * 256 + tid;        // 0..2047 half8 stores
      int ls = f & 3, bq = (f >> 2) & 3, d6 = (f >> 4) & 63, hl = f >> 10;
      half8 o = *reinterpret_cast<const half8*>(&T[(hl * 64 + d6) * 136 + bq * 32 + ls * 8]);
      *reinterpret_cast<half8*>(C2t + (((long)bq * 8 + h0 + hl) * 64 + d6) * 2048 + lbase + ls * 8) = o;
    }
  }
}

// ------------------------------ output GEMM (128x64, f16 in, fp32 out)
__global__ __launch_bounds__(256) void gemm_out(const f16* __restrict__ A,
                                                const f16* __restrict__ Bt,
                                                const float* __restrict__ bias,
                                                float* __restrict__ C) {
  __shared__ alignas(16) f16 As[2][128 * 32];
  __shared__ alignas(16) f16 Bs[2][64 * 32];
  const int tid = threadIdx.x;
  const int wave = tid >> 6, lane = tid & 63, quad = lane >> 4, l16 = lane & 15;
  const long m0 = (long)blockIdx.x * 128;
  const long n0 = (long)blockIdx.y * 64;
  const int srow = lane >> 2;
  const int scol = (lane & 3) * 8;

  const f16* Ag0 = A + (m0 + wave * 32 + srow) * EMBED + scol;
  const f16* Ag1 = A + (m0 + wave * 32 + 16 + srow) * EMBED + scol;
  const f16* Bg0 = Bt + (n0 + wave * 16 + srow) * EMBED + scol;

  gload16(Ag0, &As[0][(wave * 32) * 32]);
  gload16(Ag1, &As[0][(wave * 32 + 16) * 32]);
  gload16(Bg0, &Bs[0][(wave * 16) * 32]);
  floatx4 acc[2][4] = {};
  asm volatile("s_waitcnt vmcnt(0)" ::: "memory");
  __builtin_amdgcn_s_barrier();

#pragma unroll
  for (int ks = 0; ks < 16; ++ks) {
    const int cur = ks & 1;
    if (ks + 1 < 16) {
      const int k1 = (ks + 1) * 32;
      gload16(Ag0 + k1, &As[cur ^ 1][(wave * 32) * 32]);
      gload16(Ag1 + k1, &As[cur ^ 1][(wave * 32 + 16) * 32]);
      gload16(Bg0 + k1, &Bs[cur ^ 1][(wave * 16) * 32]);
    }
    half8 af[2], bf[4];
#pragma unroll
    for (int i = 0; i < 2; ++i)
      af[i] = *reinterpret_cast<const half8*>(&As[cur][(wave * 32 + i * 16 + l16) * 32 + quad * 8]);
#pragma unroll
    for (int j = 0; j < 4; ++j)
      bf[j] = *reinterpret_cast<const half8*>(&Bs[cur][(j * 16 + l16) * 32 + quad * 8]);
#pragma unroll
    for (int i = 0; i < 2; ++i)
#pragma unroll
      for (int j = 0; j < 4; ++j)
        acc[i][j] = __builtin_amdgcn_mfma_f32_16x16x32_f16(af[i], bf[j], acc[i][j], 0, 0, 0);
    if (ks + 1 < 16) {
      asm volatile("s_waitcnt vmcnt(0)" ::: "memory");
      __builtin_amdgcn_s_barrier();
    }
  }
#pragma unroll
  for (int i = 0; i < 2; ++i)
#pragma unroll
    for (int r = 0; r < 4; ++r) {
      long row = m0 + wave * 32 + i * 16 + quad * 4 + r;
#pragma unroll
      for (int j = 0; j < 4; ++j) {
        long col = n0 + j * 16 + l16;
        C[row * EMBED + col] = acc[i][j][r] + bias[col];
      }
    }
}

// ------------------------------------------------------------- flash attention
// R5-verified double-buffered async kernel + T1 XCD remap (FETCH 70->13 MB,
// verified R6). setprio REMOVED (R6: -3 us regression; lockstep-barrier
// structure is m190's null/negative regime, not m191's).
#define KBUFB (128 * 64 * 2)     // 16384 B per K buffer
#define VBUFB (64 * 128 * 2)     // 16384 B per V buffer
#define PEBUFB (128 * 16 * 2)    // 4096 B per PE buffer
#define LDSB (2 * KBUFB + 2 * VBUFB + 2 * PEBUFB)   // 73728 B
#define NCHUNK (SEQ_L / 128)
__global__ __launch_bounds__(512, 4) void attn_flash(const f16* __restrict__ qp,
                                                     const f16* __restrict__ kp,
                                                     const f16* __restrict__ vt,
                                                     const float* __restrict__ pe1,
                                                     const float* __restrict__ pe2,
                                                     f16* __restrict__ ao) {
  __shared__ alignas(16) unsigned char smem[LDSB];
  f16* K0 = reinterpret_cast<f16*>(smem);                       // [2][128][64]
  f16* V0 = reinterpret_cast<f16*>(smem + 2 * KBUFB);           // [2][64][128]
  f16* P0 = reinterpret_cast<f16*>(smem + 2 * KBUFB + 2 * VBUFB); // [2][128][16]
  float* comb = reinterpret_cast<float*>(smem);                 // merge region
  const int tid = threadIdx.x, wave = tid >> 6, lane = tid & 63;
  const int m = lane & 31, h = lane >> 5;
  const int strip = wave & 3, half = wave >> 2;
  // XCD-aware (q-tile, head) decode: all 16 q-tile blocks sharing one head's
  // K/V stream land on the same XCD. Bijective on [0,512).
  const int W = blockIdx.y * 16 + blockIdx.x;
  const int bh = (W & 7) + ((W >> 7) << 3);
  const int n0 = ((W >> 3) & 15) * 128;
  const int b = bh >> 3, hd = bh & 7;
  const long headoff = (long)b * EMBED + hd * HDIM;
  const long vhead = (long)bh * 64 * 2048;

  // per-lane invariant staging geometry (both-sides XOR swizzle, rule 21).
  const int krow0 = wave * 16 + (lane >> 3);            // it=0 row; it=1 adds 8
  const int kg = (lane & 7) ^ (lane >> 3);
  const f16* ksrc0 = kp + headoff + (long)krow0 * BE + kg * 8;
  const int vd0 = wave * 8 + (lane >> 4);               // it=0 ; it=1 adds 4
  const int vd1 = vd0 + 4;
  const int vg0 = (lane & 15) ^ (vd0 & 7);
  const int vg1 = (lane & 15) ^ (vd1 & 7);
  const f16* vsrc0 = vt + vhead + (long)vd0 * 2048 + vg0 * 8;
  const f16* vsrc1 = vt + vhead + (long)vd1 * 2048 + vg1 * 8;

  // ---- phase A: Q -> K buf0 (linear), V chunk0 gloads, PE zeros + pe1 ----
  for (int c = tid; c < 1024; c += 512) {
    int r = c >> 3, col = (c & 7) * 8;
    *reinterpret_cast<uint4*>(&K0[r * 64 + col]) =
        *reinterpret_cast<const uint4*>(qp + (long)(n0 + r) * BE + headoff + col);
  }
  gload16(vsrc0, V0 + wave * 1024);
  gload16(vsrc1, V0 + wave * 1024 + 512);
  if (tid < 256) {  // zero PE cols 4..15 of both buffers (256 rows total)
    const uint2 z2 = {0, 0};
    const uint4 z4 = {0, 0, 0, 0};
    *reinterpret_cast<uint2*>(reinterpret_cast<char*>(P0) + tid * 32 + 8) = z2;
    *reinterpret_cast<uint4*>(reinterpret_cast<char*>(P0) + tid * 32 + 16) = z4;
  }
  if (tid < 128) {
    long base = ((long)b * SEQ_N + n0 + tid) * 3;
    half4 v8;
    v8[0] = (f16)(pe1[base + 0] * QSCALE);
    v8[1] = (f16)(pe1[base + 1] * QSCALE);
    v8[2] = (f16)(pe1[base + 2] * QSCALE);
    v8[3] = (f16)0.f;
    *reinterpret_cast<half4*>(&P0[tid * 16]) = v8;
  }
  __syncthreads();

  // ---- phase B: read Q fragments (unswizzled; one-time) ----
  half8 qf[5];
#pragma unroll
  for (int e = 0; e < 4; ++e)
    qf[e] = *reinterpret_cast<const half8*>(&K0[(strip * 32 + m) * 64 + e * 16 + h * 8]);
  qf[4] = *reinterpret_cast<const half8*>(&P0[(strip * 32 + m) * 16 + h * 8]);
  __syncthreads();  // Q reads done; K buf0 reusable

  // ---- phase C: K chunk0 gloads + pe2 chunk0 ----
  gload16(ksrc0, K0 + wave * 1024);
  gload16(ksrc0 + 8 * BE, K0 + wave * 1024 + 512);
  {
    int pr = tid & 127;
    float a0 = pe2[(long)pr * 3 + 0];
    float a1 = pe2[(long)pr * 3 + 1];
    float a2 = pe2[(long)pr * 3 + 2];
    if (tid < 128) {
      half4 p2v; p2v[0] = (f16)a0; p2v[1] = (f16)a1; p2v[2] = (f16)a2; p2v[3] = (f16)0.f;
      *reinterpret_cast<half4*>(&P0[tid * 16]) = p2v;
    }
  }
  __syncthreads();  // implicit vmcnt(0): chunk0 staged

  floatx16 oacc[2] = {};
  float lpart = 0.f;

  auto compute_chunk = [&](int bsel) {
    const f16* Kb = K0 + bsel * 8192;
    const f16* Vb = V0 + bsel * 8192;
    const f16* Pb = P0 + bsel * 2048;
#pragma unroll
    for (int tt = 0; tt < 2; ++tt) {
      const int t = half * 2 + tt;
      const int row = t * 32 + m;
      const int r7 = m & 7;
      floatx16 st = {};
#pragma unroll
      for (int e = 0; e < 4; ++e) {
        half8 kf = *reinterpret_cast<const half8*>(&Kb[row * 64 + (((2 * e + h) ^ r7) * 8)]);
        st = __builtin_amdgcn_mfma_f32_32x32x16_f16(kf, qf[e], st, 0, 0, 0);
      }
      {
        half8 kf = *reinterpret_cast<const half8*>(&Pb[row * 16 + h * 8]);
        st = __builtin_amdgcn_mfma_f32_32x32x16_f16(kf, qf[4], st, 0, 0, 0);
      }
      float p[16];
#pragma unroll
      for (int r = 0; r < 16; ++r) {
        p[r] = fast_exp2(st[r]);
        lpart += p[r];
      }
#pragma unroll
      for (int s = 0; s < 4; ++s) {
        half2v u0 = pk2(p[4 * s + 0], p[4 * s + 1]);
        half2v u1 = pk2(p[4 * s + 2], p[4 * s + 3]);
        half4 bp;
        bp[0] = u0[0]; bp[1] = u0[1]; bp[2] = u1[0]; bp[3] = u1[1];
        const int sl = t * 4 + s;
#pragma unroll
        for (int dt = 0; dt < 2; ++dt) {
          const int d = dt * 32 + m;
          half4 vf = *reinterpret_cast<const half4*>(&Vb[d * 128 + ((sl ^ r7) * 8) + h * 4]);
          oacc[dt] = __builtin_amdgcn_mfma_f32_32x32x8f16(vf, bp, oacc[dt], 0, 0, 0);
        }
      }
    }
  };

  int buf = 0;
#pragma unroll 1
  for (int c = 0; c < NCHUNK - 1; ++c) {
    const int l0n = (c + 1) * 128;
    f16* Kn = K0 + (buf ^ 1) * 8192;
    f16* Vn = V0 + (buf ^ 1) * 8192;
    // issue chunk c+1 staging (lands while we compute chunk c)
    gload16(ksrc0 + (long)l0n * BE, Kn + wave * 1024);
    gload16(ksrc0 + (long)l0n * BE + 8 * BE, Kn + wave * 1024 + 512);
    gload16(vsrc0 + l0n, Vn + wave * 1024);
    gload16(vsrc1 + l0n, Vn + wave * 1024 + 512);
    int pr = tid & 127;
    float a0 = pe2[(long)(l0n + pr) * 3 + 0];
    float a1 = pe2[(long)(l0n + pr) * 3 + 1];
    float a2 = pe2[(long)(l0n + pr) * 3 + 2];

    compute_chunk(buf);

    if (tid < 128) {
      half4 p2v; p2v[0] = (f16)a0; p2v[1] = (f16)a1; p2v[2] = (f16)a2; p2v[3] = (f16)0.f;
      *reinterpret_cast<half4*>(&P0[(buf ^ 1) * 2048 + tid * 16]) = p2v;
    }
    __syncthreads();  // implicit vmcnt(0)+lgkmcnt(0): chunk c+1 ready
    buf ^= 1;
  }
  compute_chunk(buf);  // last chunk
  __syncthreads();     // all LDS reads done; smem reusable as comb

  lpart += __shfl_xor(lpart, 32);

  if (half == 1) {
    float* dst = comb + (strip * 64 + lane) * 33;
#pragma unroll
    for (int dt = 0; dt < 2; ++dt)
#pragma unroll
      for (int x = 0; x < 16; ++x) dst[dt * 16 + x] = oacc[dt][x];
    dst[32] = lpart;
  }
  __syncthreads();
  if (half == 0) {
    const float* src = comb + (strip * 64 + lane) * 33;
#pragma unroll
    for (int dt = 0; dt < 2; ++dt)
#pragma unroll
      for (int x = 0; x < 16; ++x) oacc[dt][x] += src[dt * 16 + x];
    float inv = 1.f / (lpart + src[32]);
    long qrow = n0 + strip * 32 + m;
#pragma unroll
    for (int dt = 0; dt < 2; ++dt)
#pragma unroll
      for (int g = 0; g < 4; ++g) {
        half4 o4;
#pragma unroll
        for (int x = 0; x < 4; ++x) o4[x] = (f16)(oacc[dt][4 * g + x] * inv);
        int d = dt * 32 + 8 * g + 4 * h;
        *reinterpret_cast<half4*>(ao + qrow * BE + headoff + d) = o4;
      }
  }
}

// ---------------------------------------------------------------------- launch
extern "C" void kernel_launch(void* const* d_in, const int* in_sizes, int n_in,
                              void* d_out, int out_size, void* d_ws, size_t ws_size,
                              hipStream_t stream) {
  const float* q   = (const float*)d_in[0];
  const float* k   = (const float*)d_in[1];
  const float* v   = (const float*)d_in[2];
  const float* pe1 = (const float*)d_in[3];
  const float* pe2 = (const float*)d_in[4];
  const float* Wq  = (const float*)d_in[5];
  const float* bq  = (const float*)d_in[6];
  const float* Wk  = (const float*)d_in[7];
  const float* bk  = (const float*)d_in[8];
  const float* Wv  = (const float*)d_in[9];
  const float* bv  = (const float*)d_in[10];
  const float* Wo  = (const float*)d_in[11];
  const float* bo  = (const float*)d_in[12];
  float* out = (float*)d_out;

  f16* ws = (f16*)d_ws;
  const long TOK = (long)MROWS * EMBED;  // 4,194,304 elements
  const long WSZ = (long)EMBED * EMBED;  //   262,144 elements
  f16* Wqb = ws;                // 4 weights contiguous: Wq,Wk,Wv,Wo
  f16* Wkb = Wqb + WSZ;
  f16* Wvb = Wkb + WSZ;
  f16* Wob = Wvb + WSZ;
  f16* qpb = Wob + WSZ;
  f16* kpb = qpb + TOK;
  f16* vtb = kpb + TOK;         // head-transposed V (written by gemm_qkv sel==2)
  f16* aob = vtb + TOK;         // attn output

  cvt_w<<<dim3(1024), 256, 0, stream>>>(Wq, Wk, Wv, Wo, Wqb);

  gemm_qkv<<<dim3(MROWS / 128, 12), 256, 0, stream>>>(q, k, v, Wqb, Wkb, Wvb,
                                                      bq, bk, bv, qpb, kpb, vtb);

  attn_flash<<<dim3(SEQ_N / 128, BATCH * NHEADS), 512, 0, stream>>>(qpb, kpb, vtb, pe1, pe2, aob);

  gemm_out<<<dim3(MROWS / 128, EMBED / 64), 256, 0, stream>>>(aob, Wob, bo, out);
}

// Round 9
// 199.765 us; speedup vs baseline: 1.0445x; 1.0445x over previous
//
#include <hip/hip_runtime.h>
#include <math.h>

#define EMBED 512
#define HDIM 64
#define NHEADS 8
#define SEQ_N 2048
#define SEQ_L 2048
#define BATCH 4
#define MROWS (SEQ_N*BATCH)   // 8192 rows, row index m = n*BATCH + b
#define BE (BATCH*EMBED)      // 2048 element row stride in (n,b,E) tensors

// scores scale folded into Q-projection and pe1: 1/sqrt(64) * log2(e)
#define QSCALE 0.18033688f

typedef _Float16 f16;
typedef _Float16 half8 __attribute__((ext_vector_type(8)));
typedef _Float16 half4 __attribute__((ext_vector_type(4)));
typedef _Float16 half2v __attribute__((ext_vector_type(2)));
typedef float floatx4 __attribute__((ext_vector_type(4)));
typedef float floatx16 __attribute__((ext_vector_type(16)));

static __device__ inline float fast_exp2(float x) {
#if __has_builtin(__builtin_amdgcn_exp2f)
  return __builtin_amdgcn_exp2f(x);
#else
  return __expf(x * 0.69314718056f);
#endif
}

static __device__ inline half2v pk2(float a, float b) {
#if __has_builtin(__builtin_amdgcn_cvt_pkrtz)
  return __builtin_bit_cast(half2v, __builtin_amdgcn_cvt_pkrtz(a, b));
#else
  half2v o; o[0] = (f16)a; o[1] = (f16)b; return o;
#endif
}

// async global->LDS 16B/lane copy: LDS dest is wave-uniform base + lane*16,
// global src is per-lane. [m97 recipe, width=16]
static __device__ inline void gload16(const void* g, void* l) {
  __builtin_amdgcn_global_load_lds(
      (__attribute__((address_space(1))) void*)(g),
      (__attribute__((address_space(3))) void*)(l), 16, 0, 0);
}

// ---------------------------------------- fused fp32->fp16 converts (1 launch)
// y<3: q/k/v token tensors (TOK elems). y==3: 4 weights, contiguous dst.
// RESTORED (R8 post-mortem): in-GEMM fp32-A staging cost gemm_qkv +28 us;
// the separate streaming convert (~16 us, near BW ceiling) is cheaper.
__global__ __launch_bounds__(256) void cvt_all(const float* __restrict__ q,
                                               const float* __restrict__ k,
                                               const float* __restrict__ v,
                                               const float* __restrict__ Wq,
                                               const float* __restrict__ Wk,
                                               const float* __restrict__ Wv,
                                               const float* __restrict__ Wo,
                                               f16* __restrict__ qb, f16* __restrict__ kb,
                                               f16* __restrict__ vb, f16* __restrict__ Wb) {
  const long TOK = (long)MROWS * EMBED;
  const long WSZ = (long)EMBED * EMBED;  // 2^18
  int y = blockIdx.y;
  long i = ((long)blockIdx.x * 256 + threadIdx.x) * 4;
  if (y < 3) {
    if (i < TOK) {
      const float* s = y == 0 ? q : y == 1 ? k : v;
      f16* d = y == 0 ? qb : y == 1 ? kb : vb;
      float4 f = *reinterpret_cast<const float4*>(s + i);
      half4 o; o[0] = (f16)f.x; o[1] = (f16)f.y; o[2] = (f16)f.z; o[3] = (f16)f.w;
      *reinterpret_cast<half4*>(d + i) = o;
    }
  } else {
    if (i < 4 * WSZ) {
      int sel = (int)(i >> 18);
      long off = i & (WSZ - 1);
      const float* s = sel == 0 ? Wq : sel == 1 ? Wk : sel == 2 ? Wv : Wo;
      float4 f = *reinterpret_cast<const float4*>(s + off);
      half4 o; o[0] = (f16)f.x; o[1] = (f16)f.y; o[2] = (f16)f.z; o[3] = (f16)f.w;
      *reinterpret_cast<half4*>(Wb + i) = o;
    }
  }
}

// ---------------------------------------- fused QKV projection GEMM (128x128)
// R6-verified f16-A form: minimum 2-phase double-buffered K-loop, async
// gload16 staging for BOTH A and B. blockIdx.y in [0,12): sel = y>>2 picks
// {q,k,v}; n0 = (y&3)*128. sel==0 output pre-scaled QSCALE. sel==2 (V):
// epilogue transposes the 128x128 tile through LDS and stores head-transposed
// V directly (coalesced half8 runs) -- verified R4 win.
__global__ __launch_bounds__(256) void gemm_qkv(const f16* __restrict__ A0,
                                                const f16* __restrict__ A1,
                                                const f16* __restrict__ A2,
                                                const f16* __restrict__ W0,
                                                const f16* __restrict__ W1,
                                                const f16* __restrict__ W2,
                                                const float* __restrict__ b0,
                                                const float* __restrict__ b1,
                                                const float* __restrict__ b2,
                                                f16* __restrict__ C0, f16* __restrict__ C1,
                                                f16* __restrict__ C2t) {
  __shared__ alignas(16) unsigned char gsm[34816];
  f16* As = reinterpret_cast<f16*>(gsm);            // [2][128*32]
  f16* Bs = reinterpret_cast<f16*>(gsm + 16384);    // [2][128*32]
  f16* T  = reinterpret_cast<f16*>(gsm);            // [128][136] (sel==2 epi)
  const int sel = blockIdx.y >> 2;
  const f16* A = sel == 0 ? A0 : sel == 1 ? A1 : A2;
  const f16* Bt = sel == 0 ? W0 : sel == 1 ? W1 : W2;
  const float* bias = sel == 0 ? b0 : sel == 1 ? b1 : b2;
  const float scl = sel == 0 ? QSCALE : 1.0f;
  const int tid = threadIdx.x;
  const int wave = tid >> 6, lane = tid & 63, quad = lane >> 4, l16 = lane & 15;
  const int wm = wave & 1, wn = wave >> 1;
  const long m0 = (long)blockIdx.x * 128;
  const long n0 = (long)(blockIdx.y & 3) * 128;
  const int srow = lane >> 2;        // 0..15 row within 16-row chunk
  const int scol = (lane & 3) * 8;   // f16 col within 32-wide tile

  const f16* Ag0 = A + (m0 + wave * 32 + srow) * EMBED + scol;
  const f16* Ag1 = A + (m0 + wave * 32 + 16 + srow) * EMBED + scol;
  const f16* Bg0 = Bt + (n0 + wave * 32 + srow) * EMBED + scol;
  const f16* Bg1 = Bt + (n0 + wave * 32 + 16 + srow) * EMBED + scol;

  gload16(Ag0, &As[(wave * 32) * 32]);
  gload16(Ag1, &As[(wave * 32 + 16) * 32]);
  gload16(Bg0, &Bs[(wave * 32) * 32]);
  gload16(Bg1, &Bs[(wave * 32 + 16) * 32]);
  floatx4 acc[4][4] = {};
  asm volatile("s_waitcnt vmcnt(0)" ::: "memory");
  __builtin_amdgcn_s_barrier();

#pragma unroll
  for (int ks = 0; ks < 16; ++ks) {
    const int cur = ks & 1;
    if (ks + 1 < 16) {
      const int k1 = (ks + 1) * 32;
      gload16(Ag0 + k1, &As[(cur ^ 1) * 4096 + (wave * 32) * 32]);
      gload16(Ag1 + k1, &As[(cur ^ 1) * 4096 + (wave * 32 + 16) * 32]);
      gload16(Bg0 + k1, &Bs[(cur ^ 1) * 4096 + (wave * 32) * 32]);
      gload16(Bg1 + k1, &Bs[(cur ^ 1) * 4096 + (wave * 32 + 16) * 32]);
    }
    half8 af[4], bf[4];
#pragma unroll
    for (int i = 0; i < 4; ++i)
      af[i] = *reinterpret_cast<const half8*>(&As[cur * 4096 + (wm * 64 + i * 16 + l16) * 32 + quad * 8]);
#pragma unroll
    for (int j = 0; j < 4; ++j)
      bf[j] = *reinterpret_cast<const half8*>(&Bs[cur * 4096 + (wn * 64 + j * 16 + l16) * 32 + quad * 8]);
#pragma unroll
    for (int i = 0; i < 4; ++i)
#pragma unroll
      for (int j = 0; j < 4; ++j)
        acc[i][j] = __builtin_amdgcn_mfma_f32_16x16x32_f16(af[i], bf[j], acc[i][j], 0, 0, 0);
    if (ks + 1 < 16) {
      asm volatile("s_waitcnt vmcnt(0)" ::: "memory");
      __builtin_amdgcn_s_barrier();
    }
  }

  if (sel != 2) {
    f16* C = sel == 0 ? C0 : C1;
#pragma unroll
    for (int i = 0; i < 4; ++i)
#pragma unroll
      for (int r = 0; r < 4; ++r) {
        long row = m0 + wm * 64 + i * 16 + quad * 4 + r;
#pragma unroll
        for (int j = 0; j < 4; ++j) {
          long col = n0 + wn * 64 + j * 16 + l16;
          float val = (acc[i][j][r] + bias[col]) * scl;
          C[row * EMBED + col] = (f16)val;
        }
      }
  } else {
    __syncthreads();  // done reading As/Bs
#pragma unroll
    for (int i = 0; i < 4; ++i)
#pragma unroll
      for (int r = 0; r < 4; ++r) {
        int mrow = wm * 64 + i * 16 + quad * 4 + r;
        int bq = mrow & 3, lt = mrow >> 2;
#pragma unroll
        for (int j = 0; j < 4; ++j) {
          int col = wn * 64 + j * 16 + l16;
          float val = acc[i][j][r] + bias[n0 + col];
          T[col * 136 + bq * 32 + lt] = (f16)val;
        }
      }
    __syncthreads();
    const int h0 = (int)(n0 >> 6);   // first head of this col-tile (2 heads)
    const long lbase = m0 >> 2;      // l-token base of this row-tile
#pragma unroll
    for (int it = 0; it < 8; ++it) {
      int f = it * 256 + tid;        // 0..2047 half8 stores
      int ls = f & 3, bq = (f >> 2) & 3, d6 = (f >> 4) & 63, hl = f >> 10;
      half8 o = *reinterpret_cast<const half8*>(&T[(hl * 64 + d6) * 136 + bq * 32 + ls * 8]);
      *reinterpret_cast<half8*>(C2t + (((long)bq * 8 + h0 + hl) * 64 + d6) * 2048 + lbase + ls * 8) = o;
    }
  }
}

// ------------------------------ output GEMM (128x64, f16 in, fp32 out)
__global__ __launch_bounds__(256) void gemm_out(const f16* __restrict__ A,
                                                const f16* __restrict__ Bt,
                                                const float* __restrict__ bias,
                                                float* __restrict__ C) {
  __shared__ alignas(16) f16 As[2][128 * 32];
  __shared__ alignas(16) f16 Bs[2][64 * 32];
  const int tid = threadIdx.x;
  const int wave = tid >> 6, lane = tid & 63, quad = lane >> 4, l16 = lane & 15;
  const long m0 = (long)blockIdx.x * 128;
  const long n0 = (long)blockIdx.y * 64;
  const int srow = lane >> 2;
  const int scol = (lane & 3) * 8;

  const f16* Ag0 = A + (m0 + wave * 32 + srow) * EMBED + scol;
  const f16* Ag1 = A + (m0 + wave * 32 + 16 + srow) * EMBED + scol;
  const f16* Bg0 = Bt + (n0 + wave * 16 + srow) * EMBED + scol;

  gload16(Ag0, &As[0][(wave * 32) * 32]);
  gload16(Ag1, &As[0][(wave * 32 + 16) * 32]);
  gload16(Bg0, &Bs[0][(wave * 16) * 32]);
  floatx4 acc[2][4] = {};
  asm volatile("s_waitcnt vmcnt(0)" ::: "memory");
  __builtin_amdgcn_s_barrier();

#pragma unroll
  for (int ks = 0; ks < 16; ++ks) {
    const int cur = ks & 1;
    if (ks + 1 < 16) {
      const int k1 = (ks + 1) * 32;
      gload16(Ag0 + k1, &As[cur ^ 1][(wave * 32) * 32]);
      gload16(Ag1 + k1, &As[cur ^ 1][(wave * 32 + 16) * 32]);
      gload16(Bg0 + k1, &Bs[cur ^ 1][(wave * 16) * 32]);
    }
    half8 af[2], bf[4];
#pragma unroll
    for (int i = 0; i < 2; ++i)
      af[i] = *reinterpret_cast<const half8*>(&As[cur][(wave * 32 + i * 16 + l16) * 32 + quad * 8]);
#pragma unroll
    for (int j = 0; j < 4; ++j)
      bf[j] = *reinterpret_cast<const half8*>(&Bs[cur][(j * 16 + l16) * 32 + quad * 8]);
#pragma unroll
    for (int i = 0; i < 2; ++i)
#pragma unroll
      for (int j = 0; j < 4; ++j)
        acc[i][j] = __builtin_amdgcn_mfma_f32_16x16x32_f16(af[i], bf[j], acc[i][j], 0, 0, 0);
    if (ks + 1 < 16) {
      asm volatile("s_waitcnt vmcnt(0)" ::: "memory");
      __builtin_amdgcn_s_barrier();
    }
  }
#pragma unroll
  for (int i = 0; i < 2; ++i)
#pragma unroll
    for (int r = 0; r < 4; ++r) {
      long row = m0 + wave * 32 + i * 16 + quad * 4 + r;
#pragma unroll
      for (int j = 0; j < 4; ++j) {
        long col = n0 + j * 16 + l16;
        C[row * EMBED + col] = acc[i][j][r] + bias[col];
      }
    }
}

// ------------------------------------------------------------- flash attention
// Best verified attn: double-buffered async gload16 staging (R5, 54.8) +
// T1 XCD remap (R6, FETCH 70->13 MB) + NO setprio (R8: 54.9 vs 57.9 with).
// K b128 reads audited at the 8-beat LDS structural floor -- the 9.6M
// bank-conflict count is floor beats, not avoidable stalls.
#define KBUFB (128 * 64 * 2)     // 16384 B per K buffer
#define VBUFB (64 * 128 * 2)     // 16384 B per V buffer
#define PEBUFB (128 * 16 * 2)    // 4096 B per PE buffer
#define LDSB (2 * KBUFB + 2 * VBUFB + 2 * PEBUFB)   // 73728 B
#define NCHUNK (SEQ_L / 128)
__global__ __launch_bounds__(512, 4) void attn_flash(const f16* __restrict__ qp,
                                                     const f16* __restrict__ kp,
                                                     const f16* __restrict__ vt,
                                                     const float* __restrict__ pe1,
                                                     const float* __restrict__ pe2,
                                                     f16* __restrict__ ao) {
  __shared__ alignas(16) unsigned char smem[LDSB];
  f16* K0 = reinterpret_cast<f16*>(smem);                       // [2][128][64]
  f16* V0 = reinterpret_cast<f16*>(smem + 2 * KBUFB);           // [2][64][128]
  f16* P0 = reinterpret_cast<f16*>(smem + 2 * KBUFB + 2 * VBUFB); // [2][128][16]
  float* comb = reinterpret_cast<float*>(smem);                 // merge region
  const int tid = threadIdx.x, wave = tid >> 6, lane = tid & 63;
  const int m = lane & 31, h = lane >> 5;
  const int strip = wave & 3, half = wave >> 2;
  // XCD-aware (q-tile, head) decode: all 16 q-tile blocks sharing one head's
  // K/V stream land on the same XCD. Bijective on [0,512).
  const int W = blockIdx.y * 16 + blockIdx.x;
  const int bh = (W & 7) + ((W >> 7) << 3);
  const int n0 = ((W >> 3) & 15) * 128;
  const int b = bh >> 3, hd = bh & 7;
  const long headoff = (long)b * EMBED + hd * HDIM;
  const long vhead = (long)bh * 64 * 2048;

  // per-lane invariant staging geometry (both-sides XOR swizzle, rule 21).
  const int krow0 = wave * 16 + (lane >> 3);            // it=0 row; it=1 adds 8
  const int kg = (lane & 7) ^ (lane >> 3);
  const f16* ksrc0 = kp + headoff + (long)krow0 * BE + kg * 8;
  const int vd0 = wave * 8 + (lane >> 4);               // it=0 ; it=1 adds 4
  const int vd1 = vd0 + 4;
  const int vg0 = (lane & 15) ^ (vd0 & 7);
  const int vg1 = (lane & 15) ^ (vd1 & 7);
  const f16* vsrc0 = vt + vhead + (long)vd0 * 2048 + vg0 * 8;
  const f16* vsrc1 = vt + vhead + (long)vd1 * 2048 + vg1 * 8;

  // ---- phase A: Q -> K buf0 (linear), V chunk0 gloads, PE zeros + pe1 ----
  for (int c = tid; c < 1024; c += 512) {
    int r = c >> 3, col = (c & 7) * 8;
    *reinterpret_cast<uint4*>(&K0[r * 64 + col]) =
        *reinterpret_cast<const uint4*>(qp + (long)(n0 + r) * BE + headoff + col);
  }
  gload16(vsrc0, V0 + wave * 1024);
  gload16(vsrc1, V0 + wave * 1024 + 512);
  if (tid < 256) {  // zero PE cols 4..15 of both buffers (256 rows total)
    const uint2 z2 = {0, 0};
    const uint4 z4 = {0, 0, 0, 0};
    *reinterpret_cast<uint2*>(reinterpret_cast<char*>(P0) + tid * 32 + 8) = z2;
    *reinterpret_cast<uint4*>(reinterpret_cast<char*>(P0) + tid * 32 + 16) = z4;
  }
  if (tid < 128) {
    long base = ((long)b * SEQ_N + n0 + tid) * 3;
    half4 v8;
    v8[0] = (f16)(pe1[base + 0] * QSCALE);
    v8[1] = (f16)(pe1[base + 1] * QSCALE);
    v8[2] = (f16)(pe1[base + 2] * QSCALE);
    v8[3] = (f16)0.f;
    *reinterpret_cast<half4*>(&P0[tid * 16]) = v8;
  }
  __syncthreads();

  // ---- phase B: read Q fragments (unswizzled; one-time) ----
  half8 qf[5];
#pragma unroll
  for (int e = 0; e < 4; ++e)
    qf[e] = *reinterpret_cast<const half8*>(&K0[(strip * 32 + m) * 64 + e * 16 + h * 8]);
  qf[4] = *reinterpret_cast<const half8*>(&P0[(strip * 32 + m) * 16 + h * 8]);
  __syncthreads();  // Q reads done; K buf0 reusable

  // ---- phase C: K chunk0 gloads + pe2 chunk0 ----
  gload16(ksrc0, K0 + wave * 1024);
  gload16(ksrc0 + 8 * BE, K0 + wave * 1024 + 512);
  {
    int pr = tid & 127;
    float a0 = pe2[(long)pr * 3 + 0];
    float a1 = pe2[(long)pr * 3 + 1];
    float a2 = pe2[(long)pr * 3 + 2];
    if (tid < 128) {
      half4 p2v; p2v[0] = (f16)a0; p2v[1] = (f16)a1; p2v[2] = (f16)a2; p2v[3] = (f16)0.f;
      *reinterpret_cast<half4*>(&P0[tid * 16]) = p2v;
    }
  }
  __syncthreads();  // implicit vmcnt(0): chunk0 staged

  floatx16 oacc[2] = {};
  float lpart = 0.f;

  auto compute_chunk = [&](int bsel) {
    const f16* Kb = K0 + bsel * 8192;
    const f16* Vb = V0 + bsel * 8192;
    const f16* Pb = P0 + bsel * 2048;
#pragma unroll
    for (int tt = 0; tt < 2; ++tt) {
      const int t = half * 2 + tt;
      const int row = t * 32 + m;
      const int r7 = m & 7;
      floatx16 st = {};
#pragma unroll
      for (int e = 0; e < 4; ++e) {
        half8 kf = *reinterpret_cast<const half8*>(&Kb[row * 64 + (((2 * e + h) ^ r7) * 8)]);
        st = __builtin_amdgcn_mfma_f32_32x32x16_f16(kf, qf[e], st, 0, 0, 0);
      }
      {
        half8 kf = *reinterpret_cast<const half8*>(&Pb[row * 16 + h * 8]);
        st = __builtin_amdgcn_mfma_f32_32x32x16_f16(kf, qf[4], st, 0, 0, 0);
      }
      float p[16];
#pragma unroll
      for (int r = 0; r < 16; ++r) {
        p[r] = fast_exp2(st[r]);
        lpart += p[r];
      }
#pragma unroll
      for (int s = 0; s < 4; ++s) {
        half2v u0 = pk2(p[4 * s + 0], p[4 * s + 1]);
        half2v u1 = pk2(p[4 * s + 2], p[4 * s + 3]);
        half4 bp;
        bp[0] = u0[0]; bp[1] = u0[1]; bp[2] = u1[0]; bp[3] = u1[1];
        const int sl = t * 4 + s;
#pragma unroll
        for (int dt = 0; dt < 2; ++dt) {
          const int d = dt * 32 + m;
          half4 vf = *reinterpret_cast<const half4*>(&Vb[d * 128 + ((sl ^ r7) * 8) + h * 4]);
          oacc[dt] = __builtin_amdgcn_mfma_f32_32x32x8f16(vf, bp, oacc[dt], 0, 0, 0);
        }
      }
    }
  };

  int buf = 0;
#pragma unroll 1
  for (int c = 0; c < NCHUNK - 1; ++c) {
    const int l0n = (c + 1) * 128;
    f16* Kn = K0 + (buf ^ 1) * 8192;
    f16* Vn = V0 + (buf ^ 1) * 8192;
    // issue chunk c+1 staging (lands while we compute chunk c)
    gload16(ksrc0 + (long)l0n * BE, Kn + wave * 1024);
    gload16(ksrc0 + (long)l0n * BE + 8 * BE, Kn + wave * 1024 + 512);
    gload16(vsrc0 + l0n, Vn + wave * 1024);
    gload16(vsrc1 + l0n, Vn + wave * 1024 + 512);
    int pr = tid & 127;
    float a0 = pe2[(long)(l0n + pr) * 3 + 0];
    float a1 = pe2[(long)(l0n + pr) * 3 + 1];
    float a2 = pe2[(long)(l0n + pr) * 3 + 2];

    compute_chunk(buf);

    if (tid < 128) {
      half4 p2v; p2v[0] = (f16)a0; p2v[1] = (f16)a1; p2v[2] = (f16)a2; p2v[3] = (f16)0.f;
      *reinterpret_cast<half4*>(&P0[(buf ^ 1) * 2048 + tid * 16]) = p2v;
    }
    __syncthreads();  // implicit vmcnt(0)+lgkmcnt(0): chunk c+1 ready
    buf ^= 1;
  }
  compute_chunk(buf);  // last chunk
  __syncthreads();     // all LDS reads done; smem reusable as comb

  lpart += __shfl_xor(lpart, 32);

  if (half == 1) {
    float* dst = comb + (strip * 64 + lane) * 33;
#pragma unroll
    for (int dt = 0; dt < 2; ++dt)
#pragma unroll
      for (int x = 0; x < 16; ++x) dst[dt * 16 + x] = oacc[dt][x];
    dst[32] = lpart;
  }
  __syncthreads();
  if (half == 0) {
    const float* src = comb + (strip * 64 + lane) * 33;
#pragma unroll
    for (int dt = 0; dt < 2; ++dt)
#pragma unroll
      for (int x = 0; x < 16; ++x) oacc[dt][x] += src[dt * 16 + x];
    float inv = 1.f / (lpart + src[32]);
    long qrow = n0 + strip * 32 + m;
#pragma unroll
    for (int dt = 0; dt < 2; ++dt)
#pragma unroll
      for (int g = 0; g < 4; ++g) {
        half4 o4;
#pragma unroll
        for (int x = 0; x < 4; ++x) o4[x] = (f16)(oacc[dt][4 * g + x] * inv);
        int d = dt * 32 + 8 * g + 4 * h;
        *reinterpret_cast<half4*>(ao + qrow * BE + headoff + d) = o4;
      }
  }
}

// ---------------------------------------------------------------------- launch
extern "C" void kernel_launch(void* const* d_in, const int* in_sizes, int n_in,
                              void* d_out, int out_size, void* d_ws, size_t ws_size,
                              hipStream_t stream) {
  const float* q   = (const float*)d_in[0];
  const float* k   = (const float*)d_in[1];
  const float* v   = (const float*)d_in[2];
  const float* pe1 = (const float*)d_in[3];
  const float* pe2 = (const float*)d_in[4];
  const float* Wq  = (const float*)d_in[5];
  const float* bq  = (const float*)d_in[6];
  const float* Wk  = (const float*)d_in[7];
  const float* bk  = (const float*)d_in[8];
  const float* Wv  = (const float*)d_in[9];
  const float* bv  = (const float*)d_in[10];
  const float* Wo  = (const float*)d_in[11];
  const float* bo  = (const float*)d_in[12];
  float* out = (float*)d_out;

  f16* ws = (f16*)d_ws;
  const long TOK = (long)MROWS * EMBED;  // 4,194,304 elements
  const long WSZ = (long)EMBED * EMBED;  //   262,144 elements
  f16* qb  = ws;
  f16* kb  = qb + TOK;
  f16* vb  = kb + TOK;
  f16* Wqb = vb + TOK;          // 4 weights contiguous: Wq,Wk,Wv,Wo
  f16* Wkb = Wqb + WSZ;
  f16* Wvb = Wkb + WSZ;
  f16* Wob = Wvb + WSZ;
  f16* qpb = Wob + WSZ;
  f16* kpb = qpb + TOK;
  f16* vtb = kpb + TOK;         // head-transposed V (written by gemm_qkv sel==2)
  f16* aob = vtb + TOK;         // attn output

  cvt_all<<<dim3(4096, 4), 256, 0, stream>>>(q, k, v, Wq, Wk, Wv, Wo, qb, kb, vb, Wqb);

  gemm_qkv<<<dim3(MROWS / 128, 12), 256, 0, stream>>>(qb, kb, vb, Wqb, Wkb, Wvb,
                                                      bq, bk, bv, qpb, kpb, vtb);

  attn_flash<<<dim3(SEQ_N / 128, BATCH * NHEADS), 512, 0, stream>>>(qpb, kpb, vtb, pe1, pe2, aob);

  gemm_out<<<dim3(MROWS / 128, EMBED / 64), 256, 0, stream>>>(aob, Wob, bo, out);
}

// Round 10
// 191.444 us; speedup vs baseline: 1.0899x; 1.0435x over previous
//
#include <hip/hip_runtime.h>
#include <math.h>

#define EMBED 512
#define HDIM 64
#define NHEADS 8
#define SEQ_N 2048
#define SEQ_L 2048
#define BATCH 4
#define MROWS (SEQ_N*BATCH)   // 8192 rows, row index m = n*BATCH + b
#define BE (BATCH*EMBED)      // 2048 element row stride in (n,b,E) tensors

// scores scale folded into Q-projection and pe1: 1/sqrt(64) * log2(e)
#define QSCALE 0.18033688f

typedef _Float16 f16;
typedef _Float16 half8 __attribute__((ext_vector_type(8)));
typedef _Float16 half4 __attribute__((ext_vector_type(4)));
typedef _Float16 half2v __attribute__((ext_vector_type(2)));
typedef float floatx4 __attribute__((ext_vector_type(4)));
typedef float floatx16 __attribute__((ext_vector_type(16)));
typedef unsigned int uint4v __attribute__((ext_vector_type(4)));

static __device__ inline float fast_exp2(float x) {
#if __has_builtin(__builtin_amdgcn_exp2f)
  return __builtin_amdgcn_exp2f(x);
#else
  return __expf(x * 0.69314718056f);
#endif
}

static __device__ inline half2v pk2(float a, float b) {
#if __has_builtin(__builtin_amdgcn_cvt_pkrtz)
  return __builtin_bit_cast(half2v, __builtin_amdgcn_cvt_pkrtz(a, b));
#else
  half2v o; o[0] = (f16)a; o[1] = (f16)b; return o;
#endif
}

// async global->LDS 16B/lane copy: LDS dest is wave-uniform base + lane*16,
// global src is per-lane. [m97 recipe, width=16]
static __device__ inline void gload16(const void* g, void* l) {
  __builtin_amdgcn_global_load_lds(
      (__attribute__((address_space(1))) void*)(g),
      (__attribute__((address_space(3))) void*)(l), 16, 0, 0);
}

// ---------------------------------------- fused fp32->fp16 converts (1 launch)
// y<3: q/k/v token tensors (TOK elems). y==3: 4 weights, contiguous dst.
__global__ __launch_bounds__(256) void cvt_all(const float* __restrict__ q,
                                               const float* __restrict__ k,
                                               const float* __restrict__ v,
                                               const float* __restrict__ Wq,
                                               const float* __restrict__ Wk,
                                               const float* __restrict__ Wv,
                                               const float* __restrict__ Wo,
                                               f16* __restrict__ qb, f16* __restrict__ kb,
                                               f16* __restrict__ vb, f16* __restrict__ Wb) {
  const long TOK = (long)MROWS * EMBED;
  const long WSZ = (long)EMBED * EMBED;  // 2^18
  int y = blockIdx.y;
  long i = ((long)blockIdx.x * 256 + threadIdx.x) * 4;
  if (y < 3) {
    if (i < TOK) {
      const float* s = y == 0 ? q : y == 1 ? k : v;
      f16* d = y == 0 ? qb : y == 1 ? kb : vb;
      float4 f = *reinterpret_cast<const float4*>(s + i);
      half4 o; o[0] = (f16)f.x; o[1] = (f16)f.y; o[2] = (f16)f.z; o[3] = (f16)f.w;
      *reinterpret_cast<half4*>(d + i) = o;
    }
  } else {
    if (i < 4 * WSZ) {
      int sel = (int)(i >> 18);
      long off = i & (WSZ - 1);
      const float* s = sel == 0 ? Wq : sel == 1 ? Wk : sel == 2 ? Wv : Wo;
      float4 f = *reinterpret_cast<const float4*>(s + off);
      half4 o; o[0] = (f16)f.x; o[1] = (f16)f.y; o[2] = (f16)f.z; o[3] = (f16)f.w;
      *reinterpret_cast<half4*>(Wb + i) = o;
    }
  }
}

// ---------------------------------------- fused QKV projection GEMM (128x128)
// R6-verified f16-A form: minimum 2-phase double-buffered K-loop, async
// gload16 staging for BOTH A and B. sel==0 pre-scaled QSCALE. sel==2 (V):
// epilogue transposes the 128x128 tile through LDS, stores head-transposed V.
__global__ __launch_bounds__(256) void gemm_qkv(const f16* __restrict__ A0,
                                                const f16* __restrict__ A1,
                                                const f16* __restrict__ A2,
                                                const f16* __restrict__ W0,
                                                const f16* __restrict__ W1,
                                                const f16* __restrict__ W2,
                                                const float* __restrict__ b0,
                                                const float* __restrict__ b1,
                                                const float* __restrict__ b2,
                                                f16* __restrict__ C0, f16* __restrict__ C1,
                                                f16* __restrict__ C2t) {
  __shared__ alignas(16) unsigned char gsm[34816];
  f16* As = reinterpret_cast<f16*>(gsm);            // [2][128*32]
  f16* Bs = reinterpret_cast<f16*>(gsm + 16384);    // [2][128*32]
  f16* T  = reinterpret_cast<f16*>(gsm);            // [128][136] (sel==2 epi)
  const int sel = blockIdx.y >> 2;
  const f16* A = sel == 0 ? A0 : sel == 1 ? A1 : A2;
  const f16* Bt = sel == 0 ? W0 : sel == 1 ? W1 : W2;
  const float* bias = sel == 0 ? b0 : sel == 1 ? b1 : b2;
  const float scl = sel == 0 ? QSCALE : 1.0f;
  const int tid = threadIdx.x;
  const int wave = tid >> 6, lane = tid & 63, quad = lane >> 4, l16 = lane & 15;
  const int wm = wave & 1, wn = wave >> 1;
  const long m0 = (long)blockIdx.x * 128;
  const long n0 = (long)(blockIdx.y & 3) * 128;
  const int srow = lane >> 2;        // 0..15 row within 16-row chunk
  const int scol = (lane & 3) * 8;   // f16 col within 32-wide tile

  const f16* Ag0 = A + (m0 + wave * 32 + srow) * EMBED + scol;
  const f16* Ag1 = A + (m0 + wave * 32 + 16 + srow) * EMBED + scol;
  const f16* Bg0 = Bt + (n0 + wave * 32 + srow) * EMBED + scol;
  const f16* Bg1 = Bt + (n0 + wave * 32 + 16 + srow) * EMBED + scol;

  gload16(Ag0, &As[(wave * 32) * 32]);
  gload16(Ag1, &As[(wave * 32 + 16) * 32]);
  gload16(Bg0, &Bs[(wave * 32) * 32]);
  gload16(Bg1, &Bs[(wave * 32 + 16) * 32]);
  floatx4 acc[4][4] = {};
  asm volatile("s_waitcnt vmcnt(0)" ::: "memory");
  __builtin_amdgcn_s_barrier();

#pragma unroll
  for (int ks = 0; ks < 16; ++ks) {
    const int cur = ks & 1;
    if (ks + 1 < 16) {
      const int k1 = (ks + 1) * 32;
      gload16(Ag0 + k1, &As[(cur ^ 1) * 4096 + (wave * 32) * 32]);
      gload16(Ag1 + k1, &As[(cur ^ 1) * 4096 + (wave * 32 + 16) * 32]);
      gload16(Bg0 + k1, &Bs[(cur ^ 1) * 4096 + (wave * 32) * 32]);
      gload16(Bg1 + k1, &Bs[(cur ^ 1) * 4096 + (wave * 32 + 16) * 32]);
    }
    half8 af[4], bf[4];
#pragma unroll
    for (int i = 0; i < 4; ++i)
      af[i] = *reinterpret_cast<const half8*>(&As[cur * 4096 + (wm * 64 + i * 16 + l16) * 32 + quad * 8]);
#pragma unroll
    for (int j = 0; j < 4; ++j)
      bf[j] = *reinterpret_cast<const half8*>(&Bs[cur * 4096 + (wn * 64 + j * 16 + l16) * 32 + quad * 8]);
#pragma unroll
    for (int i = 0; i < 4; ++i)
#pragma unroll
      for (int j = 0; j < 4; ++j)
        acc[i][j] = __builtin_amdgcn_mfma_f32_16x16x32_f16(af[i], bf[j], acc[i][j], 0, 0, 0);
    if (ks + 1 < 16) {
      asm volatile("s_waitcnt vmcnt(0)" ::: "memory");
      __builtin_amdgcn_s_barrier();
    }
  }

  if (sel != 2) {
    f16* C = sel == 0 ? C0 : C1;
#pragma unroll
    for (int i = 0; i < 4; ++i)
#pragma unroll
      for (int r = 0; r < 4; ++r) {
        long row = m0 + wm * 64 + i * 16 + quad * 4 + r;
#pragma unroll
        for (int j = 0; j < 4; ++j) {
          long col = n0 + wn * 64 + j * 16 + l16;
          float val = (acc[i][j][r] + bias[col]) * scl;
          C[row * EMBED + col] = (f16)val;
        }
      }
  } else {
    __syncthreads();  // done reading As/Bs
#pragma unroll
    for (int i = 0; i < 4; ++i)
#pragma unroll
      for (int r = 0; r < 4; ++r) {
        int mrow = wm * 64 + i * 16 + quad * 4 + r;
        int bq = mrow & 3, lt = mrow >> 2;
#pragma unroll
        for (int j = 0; j < 4; ++j) {
          int col = wn * 64 + j * 16 + l16;
          float val = acc[i][j][r] + bias[n0 + col];
          T[col * 136 + bq * 32 + lt] = (f16)val;
        }
      }
    __syncthreads();
    const int h0 = (int)(n0 >> 6);   // first head of this col-tile (2 heads)
    const long lbase = m0 >> 2;      // l-token base of this row-tile
#pragma unroll
    for (int it = 0; it < 8; ++it) {
      int f = it * 256 + tid;        // 0..2047 half8 stores
      int ls = f & 3, bq = (f >> 2) & 3, d6 = (f >> 4) & 63, hl = f >> 10;
      half8 o = *reinterpret_cast<const half8*>(&T[(hl * 64 + d6) * 136 + bq * 32 + ls * 8]);
      *reinterpret_cast<half8*>(C2t + (((long)bq * 8 + h0 + hl) * 64 + d6) * 2048 + lbase + ls * 8) = o;
    }
  }
}

// ------------------------------ output GEMM (128x64, f16 in, fp32 out)
__global__ __launch_bounds__(256) void gemm_out(const f16* __restrict__ A,
                                                const f16* __restrict__ Bt,
                                                const float* __restrict__ bias,
                                                float* __restrict__ C) {
  __shared__ alignas(16) f16 As[2][128 * 32];
  __shared__ alignas(16) f16 Bs[2][64 * 32];
  const int tid = threadIdx.x;
  const int wave = tid >> 6, lane = tid & 63, quad = lane >> 4, l16 = lane & 15;
  const long m0 = (long)blockIdx.x * 128;
  const long n0 = (long)blockIdx.y * 64;
  const int srow = lane >> 2;
  const int scol = (lane & 3) * 8;

  const f16* Ag0 = A + (m0 + wave * 32 + srow) * EMBED + scol;
  const f16* Ag1 = A + (m0 + wave * 32 + 16 + srow) * EMBED + scol;
  const f16* Bg0 = Bt + (n0 + wave * 16 + srow) * EMBED + scol;

  gload16(Ag0, &As[0][(wave * 32) * 32]);
  gload16(Ag1, &As[0][(wave * 32 + 16) * 32]);
  gload16(Bg0, &Bs[0][(wave * 16) * 32]);
  floatx4 acc[2][4] = {};
  asm volatile("s_waitcnt vmcnt(0)" ::: "memory");
  __builtin_amdgcn_s_barrier();

#pragma unroll
  for (int ks = 0; ks < 16; ++ks) {
    const int cur = ks & 1;
    if (ks + 1 < 16) {
      const int k1 = (ks + 1) * 32;
      gload16(Ag0 + k1, &As[cur ^ 1][(wave * 32) * 32]);
      gload16(Ag1 + k1, &As[cur ^ 1][(wave * 32 + 16) * 32]);
      gload16(Bg0 + k1, &Bs[cur ^ 1][(wave * 16) * 32]);
    }
    half8 af[2], bf[4];
#pragma unroll
    for (int i = 0; i < 2; ++i)
      af[i] = *reinterpret_cast<const half8*>(&As[cur][(wave * 32 + i * 16 + l16) * 32 + quad * 8]);
#pragma unroll
    for (int j = 0; j < 4; ++j)
      bf[j] = *reinterpret_cast<const half8*>(&Bs[cur][(j * 16 + l16) * 32 + quad * 8]);
#pragma unroll
    for (int i = 0; i < 2; ++i)
#pragma unroll
      for (int j = 0; j < 4; ++j)
        acc[i][j] = __builtin_amdgcn_mfma_f32_16x16x32_f16(af[i], bf[j], acc[i][j], 0, 0, 0);
    if (ks + 1 < 16) {
      asm volatile("s_waitcnt vmcnt(0)" ::: "memory");
      __builtin_amdgcn_s_barrier();
    }
  }
#pragma unroll
  for (int i = 0; i < 2; ++i)
#pragma unroll
    for (int r = 0; r < 4; ++r) {
      long row = m0 + wave * 32 + i * 16 + quad * 4 + r;
#pragma unroll
      for (int j = 0; j < 4; ++j) {
        long col = n0 + j * 16 + l16;
        C[row * EMBED + col] = acc[i][j][r] + bias[col];
      }
    }
}

// ------------------------------------------------------------- flash attention
// R9 baseline + PV moved from 8x mfma_32x32x8 (legacy half-rate shape) to
// 4x mfma_32x32x16 (gfx950 full-rate) per t-tile. B-fragment (P) for K=16
// needs 8 consecutive l per lane; after swapped QK^T each lane owns
// interleaved 4-blocks (l = s*8 + h*4 + j) -> 2x v_permlane32_swap_b32 per
// K=16 slice exchanges the 4-halves across lane<32/lane>=32 (T12 primitive).
// V read widens to half8 at the same involution swizzle (exact 8-beat floor).
#define KBUFB (128 * 64 * 2)     // 16384 B per K buffer
#define VBUFB (64 * 128 * 2)     // 16384 B per V buffer
#define PEBUFB (128 * 16 * 2)    // 4096 B per PE buffer
#define LDSB (2 * KBUFB + 2 * VBUFB + 2 * PEBUFB)   // 73728 B
#define NCHUNK (SEQ_L / 128)
__global__ __launch_bounds__(512, 4) void attn_flash(const f16* __restrict__ qp,
                                                     const f16* __restrict__ kp,
                                                     const f16* __restrict__ vt,
                                                     const float* __restrict__ pe1,
                                                     const float* __restrict__ pe2,
                                                     f16* __restrict__ ao) {
  __shared__ alignas(16) unsigned char smem[LDSB];
  f16* K0 = reinterpret_cast<f16*>(smem);                       // [2][128][64]
  f16* V0 = reinterpret_cast<f16*>(smem + 2 * KBUFB);           // [2][64][128]
  f16* P0 = reinterpret_cast<f16*>(smem + 2 * KBUFB + 2 * VBUFB); // [2][128][16]
  float* comb = reinterpret_cast<float*>(smem);                 // merge region
  const int tid = threadIdx.x, wave = tid >> 6, lane = tid & 63;
  const int m = lane & 31, h = lane >> 5;
  const int strip = wave & 3, half = wave >> 2;
  // XCD-aware (q-tile, head) decode: all 16 q-tile blocks sharing one head's
  // K/V stream land on the same XCD. Bijective on [0,512).
  const int W = blockIdx.y * 16 + blockIdx.x;
  const int bh = (W & 7) + ((W >> 7) << 3);
  const int n0 = ((W >> 3) & 15) * 128;
  const int b = bh >> 3, hd = bh & 7;
  const long headoff = (long)b * EMBED + hd * HDIM;
  const long vhead = (long)bh * 64 * 2048;

  // per-lane invariant staging geometry (both-sides XOR swizzle, rule 21).
  const int krow0 = wave * 16 + (lane >> 3);            // it=0 row; it=1 adds 8
  const int kg = (lane & 7) ^ (lane >> 3);
  const f16* ksrc0 = kp + headoff + (long)krow0 * BE + kg * 8;
  const int vd0 = wave * 8 + (lane >> 4);               // it=0 ; it=1 adds 4
  const int vd1 = vd0 + 4;
  const int vg0 = (lane & 15) ^ (vd0 & 7);
  const int vg1 = (lane & 15) ^ (vd1 & 7);
  const f16* vsrc0 = vt + vhead + (long)vd0 * 2048 + vg0 * 8;
  const f16* vsrc1 = vt + vhead + (long)vd1 * 2048 + vg1 * 8;

  // ---- phase A: Q -> K buf0 (linear), V chunk0 gloads, PE zeros + pe1 ----
  for (int c = tid; c < 1024; c += 512) {
    int r = c >> 3, col = (c & 7) * 8;
    *reinterpret_cast<uint4*>(&K0[r * 64 + col]) =
        *reinterpret_cast<const uint4*>(qp + (long)(n0 + r) * BE + headoff + col);
  }
  gload16(vsrc0, V0 + wave * 1024);
  gload16(vsrc1, V0 + wave * 1024 + 512);
  if (tid < 256) {  // zero PE cols 4..15 of both buffers (256 rows total)
    const uint2 z2 = {0, 0};
    const uint4 z4 = {0, 0, 0, 0};
    *reinterpret_cast<uint2*>(reinterpret_cast<char*>(P0) + tid * 32 + 8) = z2;
    *reinterpret_cast<uint4*>(reinterpret_cast<char*>(P0) + tid * 32 + 16) = z4;
  }
  if (tid < 128) {
    long base = ((long)b * SEQ_N + n0 + tid) * 3;
    half4 v8;
    v8[0] = (f16)(pe1[base + 0] * QSCALE);
    v8[1] = (f16)(pe1[base + 1] * QSCALE);
    v8[2] = (f16)(pe1[base + 2] * QSCALE);
    v8[3] = (f16)0.f;
    *reinterpret_cast<half4*>(&P0[tid * 16]) = v8;
  }
  __syncthreads();

  // ---- phase B: read Q fragments (unswizzled; one-time) ----
  half8 qf[5];
#pragma unroll
  for (int e = 0; e < 4; ++e)
    qf[e] = *reinterpret_cast<const half8*>(&K0[(strip * 32 + m) * 64 + e * 16 + h * 8]);
  qf[4] = *reinterpret_cast<const half8*>(&P0[(strip * 32 + m) * 16 + h * 8]);
  __syncthreads();  // Q reads done; K buf0 reusable

  // ---- phase C: K chunk0 gloads + pe2 chunk0 ----
  gload16(ksrc0, K0 + wave * 1024);
  gload16(ksrc0 + 8 * BE, K0 + wave * 1024 + 512);
  {
    int pr = tid & 127;
    float a0 = pe2[(long)pr * 3 + 0];
    float a1 = pe2[(long)pr * 3 + 1];
    float a2 = pe2[(long)pr * 3 + 2];
    if (tid < 128) {
      half4 p2v; p2v[0] = (f16)a0; p2v[1] = (f16)a1; p2v[2] = (f16)a2; p2v[3] = (f16)0.f;
      *reinterpret_cast<half4*>(&P0[tid * 16]) = p2v;
    }
  }
  __syncthreads();  // implicit vmcnt(0): chunk0 staged

  floatx16 oacc[2] = {};
  float lpart = 0.f;

  auto compute_chunk = [&](int bsel) {
    const f16* Kb = K0 + bsel * 8192;
    const f16* Vb = V0 + bsel * 8192;
    const f16* Pb = P0 + bsel * 2048;
#pragma unroll
    for (int tt = 0; tt < 2; ++tt) {
      const int t = half * 2 + tt;
      const int row = t * 32 + m;
      const int r7 = m & 7;
      floatx16 st = {};
#pragma unroll
      for (int e = 0; e < 4; ++e) {
        half8 kf = *reinterpret_cast<const half8*>(&Kb[row * 64 + (((2 * e + h) ^ r7) * 8)]);
        st = __builtin_amdgcn_mfma_f32_32x32x16_f16(kf, qf[e], st, 0, 0, 0);
      }
      {
        half8 kf = *reinterpret_cast<const half8*>(&Pb[row * 16 + h * 8]);
        st = __builtin_amdgcn_mfma_f32_32x32x16_f16(kf, qf[4], st, 0, 0, 0);
      }
      float p[16];
#pragma unroll
      for (int r = 0; r < 16; ++r) {
        p[r] = fast_exp2(st[r]);
        lpart += p[r];
      }
      // PV with K=16: per slice u, lane needs P[l = t*32 + u*16 + h*8 + 0..7].
      // Own regs hold l = u*16 + h*4 + j (A half) and u*16 + 8 + h*4 + j (B
      // half); permlane32_swap(A,B) yields per-lane exactly the needed 8.
#pragma unroll
      for (int u = 0; u < 2; ++u) {
        unsigned a0 = __builtin_bit_cast(unsigned, pk2(p[8 * u + 0], p[8 * u + 1]));
        unsigned a1 = __builtin_bit_cast(unsigned, pk2(p[8 * u + 2], p[8 * u + 3]));
        unsigned b0 = __builtin_bit_cast(unsigned, pk2(p[8 * u + 4], p[8 * u + 5]));
        unsigned b1 = __builtin_bit_cast(unsigned, pk2(p[8 * u + 6], p[8 * u + 7]));
        // vdst[32:63] <-> vsrc[0:31]:
        //   h=0 lane: a' = own(l 0..1 of half), b' = partner(l 4..5 shifted)
        //   h=1 lane: a' = partner upper half, b' = own upper half
        asm("v_permlane32_swap_b32 %0, %1" : "+v"(a0), "+v"(b0));
        asm("v_permlane32_swap_b32 %0, %1" : "+v"(a1), "+v"(b1));
        uint4v pkd; pkd.x = a0; pkd.y = a1; pkd.z = b0; pkd.w = b1;
        half8 bp = __builtin_bit_cast(half8, pkd);
        const int s8 = t * 4 + u * 2 + h;   // 8-elem slot of this lane's l-range
#pragma unroll
        for (int dt = 0; dt < 2; ++dt) {
          const int d = dt * 32 + m;
          half8 vf = *reinterpret_cast<const half8*>(&Vb[d * 128 + ((s8 ^ r7) * 8)]);
          oacc[dt] = __builtin_amdgcn_mfma_f32_32x32x16_f16(vf, bp, oacc[dt], 0, 0, 0);
        }
      }
    }
  };

  int buf = 0;
#pragma unroll 1
  for (int c = 0; c < NCHUNK - 1; ++c) {
    const int l0n = (c + 1) * 128;
    f16* Kn = K0 + (buf ^ 1) * 8192;
    f16* Vn = V0 + (buf ^ 1) * 8192;
    // issue chunk c+1 staging (lands while we compute chunk c)
    gload16(ksrc0 + (long)l0n * BE, Kn + wave * 1024);
    gload16(ksrc0 + (long)l0n * BE + 8 * BE, Kn + wave * 1024 + 512);
    gload16(vsrc0 + l0n, Vn + wave * 1024);
    gload16(vsrc1 + l0n, Vn + wave * 1024 + 512);
    int pr = tid & 127;
    float a0 = pe2[(long)(l0n + pr) * 3 + 0];
    float a1 = pe2[(long)(l0n + pr) * 3 + 1];
    float a2 = pe2[(long)(l0n + pr) * 3 + 2];

    compute_chunk(buf);

    if (tid < 128) {
      half4 p2v; p2v[0] = (f16)a0; p2v[1] = (f16)a1; p2v[2] = (f16)a2; p2v[3] = (f16)0.f;
      *reinterpret_cast<half4*>(&P0[(buf ^ 1) * 2048 + tid * 16]) = p2v;
    }
    __syncthreads();  // implicit vmcnt(0)+lgkmcnt(0): chunk c+1 ready
    buf ^= 1;
  }
  compute_chunk(buf);  // last chunk
  __syncthreads();     // all LDS reads done; smem reusable as comb

  lpart += __shfl_xor(lpart, 32);

  if (half == 1) {
    float* dst = comb + (strip * 64 + lane) * 33;
#pragma unroll
    for (int dt = 0; dt < 2; ++dt)
#pragma unroll
      for (int x = 0; x < 16; ++x) dst[dt * 16 + x] = oacc[dt][x];
    dst[32] = lpart;
  }
  __syncthreads();
  if (half == 0) {
    const float* src = comb + (strip * 64 + lane) * 33;
#pragma unroll
    for (int dt = 0; dt < 2; ++dt)
#pragma unroll
      for (int x = 0; x < 16; ++x) oacc[dt][x] += src[dt * 16 + x];
    float inv = 1.f / (lpart + src[32]);
    long qrow = n0 + strip * 32 + m;
#pragma unroll
    for (int dt = 0; dt < 2; ++dt)
#pragma unroll
      for (int g = 0; g < 4; ++g) {
        half4 o4;
#pragma unroll
        for (int x = 0; x < 4; ++x) o4[x] = (f16)(oacc[dt][4 * g + x] * inv);
        int d = dt * 32 + 8 * g + 4 * h;
        *reinterpret_cast<half4*>(ao + qrow * BE + headoff + d) = o4;
      }
  }
}

// ---------------------------------------------------------------------- launch
extern "C" void kernel_launch(void* const* d_in, const int* in_sizes, int n_in,
                              void* d_out, int out_size, void* d_ws, size_t ws_size,
                              hipStream_t stream) {
  const float* q   = (const float*)d_in[0];
  const float* k   = (const float*)d_in[1];
  const float* v   = (const float*)d_in[2];
  const float* pe1 = (const float*)d_in[3];
  const float* pe2 = (const float*)d_in[4];
  const float* Wq  = (const float*)d_in[5];
  const float* bq  = (const float*)d_in[6];
  const float* Wk  = (const float*)d_in[7];
  const float* bk  = (const float*)d_in[8];
  const float* Wv  = (const float*)d_in[9];
  const float* bv  = (const float*)d_in[10];
  const float* Wo  = (const float*)d_in[11];
  const float* bo  = (const float*)d_in[12];
  float* out = (float*)d_out;

  f16* ws = (f16*)d_ws;
  const long TOK = (long)MROWS * EMBED;  // 4,194,304 elements
  const long WSZ = (long)EMBED * EMBED;  //   262,144 elements
  f16* qb  = ws;
  f16* kb  = qb + TOK;
  f16* vb  = kb + TOK;
  f16* Wqb = vb + TOK;          // 4 weights contiguous: Wq,Wk,Wv,Wo
  f16* Wkb = Wqb + WSZ;
  f16* Wvb = Wkb + WSZ;
  f16* Wob = Wvb + WSZ;
  f16* qpb = Wob + WSZ;
  f16* kpb = qpb + TOK;
  f16* vtb = kpb + TOK;         // head-transposed V (written by gemm_qkv sel==2)
  f16* aob = vtb + TOK;         // attn output

  cvt_all<<<dim3(4096, 4), 256, 0, stream>>>(q, k, v, Wq, Wk, Wv, Wo, qb, kb, vb, Wqb);

  gemm_qkv<<<dim3(MROWS / 128, 12), 256, 0, stream>>>(qb, kb, vb, Wqb, Wkb, Wvb,
                                                      bq, bk, bv, qpb, kpb, vtb);

  attn_flash<<<dim3(SEQ_N / 128, BATCH * NHEADS), 512, 0, stream>>>(qpb, kpb, vtb, pe1, pe2, aob);

  gemm_out<<<dim3(MROWS / 128, EMBED / 64), 256, 0, stream>>>(aob, Wob, bo, out);
}